// Round 3
// baseline (568.432 us; speedup 1.0000x reference)
//
#include <hip/hip_runtime.h>

#define EPS 1e-5f
#define LOG2E 1.4426950408889634f
// 1/sqrt(32) * log2(e), folded so the QK^T MFMA output is already in exp2 domain
#define QSCALE (0.17677669529663687f * 1.4426950408889634f)

typedef __attribute__((ext_vector_type(8))) short bf16x8;
typedef __attribute__((ext_vector_type(4))) float f32x4;

#if __has_builtin(__builtin_amdgcn_exp2f)
#define EXP2F(x) __builtin_amdgcn_exp2f(x)
#else
#define EXP2F(x) exp2f(x)
#endif

__device__ __forceinline__ unsigned short f2bf(float f) {
  unsigned u = __float_as_uint(f);
  return (unsigned short)((u + 0x7FFFu + ((u >> 16) & 1u)) >> 16);
}
__device__ __forceinline__ float bflo(unsigned u) { return __uint_as_float(u << 16); }
__device__ __forceinline__ float bfhi(unsigned u) { return __uint_as_float(u & 0xFFFF0000u); }

// ---------------- Kernel A: DynamicPosBias MLP -> posT[6][945] ----------------
__global__ void pos_mlp_kernel(const float* __restrict__ rpe,
                               const float* __restrict__ pw0, const float* __restrict__ pb0,
                               const float* __restrict__ g1, const float* __restrict__ be1,
                               const float* __restrict__ w1, const float* __restrict__ b1,
                               const float* __restrict__ g2, const float* __restrict__ be2,
                               const float* __restrict__ w2, const float* __restrict__ b2,
                               const float* __restrict__ g3, const float* __restrict__ be3,
                               const float* __restrict__ w3, const float* __restrict__ b3,
                               float* __restrict__ posT) {
  int r = blockIdx.x * blockDim.x + threadIdx.x;
  if (r >= 945) return;
  float a = rpe[2 * r], c = rpe[2 * r + 1];
  float x[12], y[12];
#pragma unroll
  for (int i = 0; i < 12; ++i) x[i] = pw0[2 * i] * a + pw0[2 * i + 1] * c + pb0[i];

  auto stage = [&](const float* g, const float* be, const float* w, const float* bb,
                   const float* in, float* outv, int dout) {
    float m = 0.f;
#pragma unroll
    for (int i = 0; i < 12; ++i) m += in[i];
    m *= (1.f / 12.f);
    float v = 0.f;
#pragma unroll
    for (int i = 0; i < 12; ++i) { float d = in[i] - m; v += d * d; }
    v *= (1.f / 12.f);
    float rs = rsqrtf(v + EPS);
    float t[12];
#pragma unroll
    for (int i = 0; i < 12; ++i) t[i] = fmaxf((in[i] - m) * rs * g[i] + be[i], 0.f);
    for (int o = 0; o < dout; ++o) {
      float s = bb[o];
#pragma unroll
      for (int i = 0; i < 12; ++i) s += w[o * 12 + i] * t[i];
      outv[o] = s;
    }
  };
  stage(g1, be1, w1, b1, x, y, 12);
  stage(g2, be2, w2, b2, y, x, 12);
  stage(g3, be3, w3, b3, x, y, 6);
#pragma unroll
  for (int h = 0; h < 6; ++h) posT[h * 945 + r] = y[h];
}

// ---------------- Kernel B: gather rpb bf16 (pre-scaled by log2e) ----------------
// per-head layout: idx = (key>>5)*8192 + q*32 + (key&31)   [chunk][q][key-in-chunk]
__global__ void rpb_gather_swz(const int* __restrict__ rpi, const float* __restrict__ posT,
                               unsigned short* __restrict__ rpb) {
  int n2 = blockIdx.x * 256 + threadIdx.x;  // 65536 total: q*256+key
  int q = n2 >> 8, key = n2 & 255;
  int idx = rpi[n2];
  int s = ((key >> 5) << 13) + (q << 5) + (key & 31);
#pragma unroll
  for (int h = 0; h < 6; ++h) rpb[(h << 16) + s] = f2bf(posT[h * 945 + idx] * LOG2E);
}

// ---------------- Kernel C: mask f32 -> bf16 (pre-scaled by log2e), [chunk][q][key] ----------------
// thread per (wimg, q, k8): reads 8 consecutive keys, writes one uint4 (8 bf16)
__global__ void mask_cvt_swz(const float* __restrict__ src, uint4* __restrict__ dst) {
  int g = blockIdx.x * 256 + threadIdx.x;  // 1048576 total
  int wimg = g >> 13;
  int rem = g & 8191;
  int q = rem >> 5;
  int k8 = rem & 31;
  const float* m = src + ((size_t)wimg << 16) + (q << 8) + (k8 << 3);
  float4 a0 = *(const float4*)m;
  float4 a1 = *(const float4*)(m + 4);
  unsigned v0 = (unsigned)f2bf(a0.x * LOG2E) | ((unsigned)f2bf(a0.y * LOG2E) << 16);
  unsigned v1 = (unsigned)f2bf(a0.z * LOG2E) | ((unsigned)f2bf(a0.w * LOG2E) << 16);
  unsigned v2 = (unsigned)f2bf(a1.x * LOG2E) | ((unsigned)f2bf(a1.y * LOG2E) << 16);
  unsigned v3 = (unsigned)f2bf(a1.z * LOG2E) | ((unsigned)f2bf(a1.w * LOG2E) << 16);
  uint4 o; o.x = v0; o.y = v1; o.z = v2; o.w = v3;
  // ushort index: wimg*65536 + (k8>>2)*8192 + q*32 + (k8&3)*8 ; /8 for uint4
  dst[(((size_t)wimg << 16) + ((k8 >> 2) << 13) + (q << 5) + ((k8 & 3) << 3)) >> 3] = o;
}

// ---------------- Main attention kernel ----------------
// grid = (512 windows, 6 heads), block = 512 threads (8 waves, 32 q-rows/wave).
// Swapped QK^T (S^T = mfma(K,Q)) with PERMUTED K-row staging so that the S^T
// output regs at lane (quad,l16) are exactly keys 8*quad+{0..3} (S0) and
// 8*quad+{4..7} (S1): the PV A-fragment (k = quad*8+j) is then lane-local —
// no cross-lane ops, no P LDS buffer. LDS 37376 B -> 3 blocks/CU, 6 waves/EU.
template <int USEBF>
__global__ __launch_bounds__(512, 6) void attn_kernel(
    const float* __restrict__ qkv, const float* __restrict__ maskf,
    const unsigned short* __restrict__ maskb, const unsigned short* __restrict__ rpb,
    float* __restrict__ out) {
  __shared__ unsigned short Kb[10240];  // [row 256][40]; row = permuted token
  __shared__ unsigned short Vt[8448];   // [ch 32][264], natural token order

  const int tid = threadIdx.x;
  const int wv = tid >> 6;
  const int lane = tid & 63;
  const int quad = lane >> 4;
  const int l16 = lane & 15;
  const int wIdx = blockIdx.x, h = blockIdx.y;
  const int b = wIdx >> 7, wimg = wIdx & 127;
  const int wh = wimg >> 3, ww = wimg & 7;

  // ---- stage K (row-permuted) and V^T into LDS (bf16) ----
  {
    const int tok = tid >> 3;         // 0..63
    const int c4 = (tid & 7) << 2;    // 0,4,...,28
#pragma unroll
    for (int p = 0; p < 4; ++p) {
      int n = (p << 6) + tok;
      int i = n >> 5, j = n & 31;
      int l = ((wh << 3) + i) * 256 + (ww << 5) + j;
      const float* kp = qkv + ((size_t)((4 + b) * 32768 + l)) * 192 + h * 32 + c4;
      const float* vp = qkv + ((size_t)((8 + b) * 32768 + l)) * 192 + h * 32 + c4;
      float4 kk = *(const float4*)kp;
      float4 vvv = *(const float4*)vp;
      unsigned long long pk = (unsigned long long)f2bf(kk.x) |
                              ((unsigned long long)f2bf(kk.y) << 16) |
                              ((unsigned long long)f2bf(kk.z) << 32) |
                              ((unsigned long long)f2bf(kk.w) << 48);
      // token offset c = 8a + 4b' + r  ->  row offset 16b' + 4a + r
      int c = n & 31;
      int rowp = (n & ~31) | ((c & 4) << 2) | ((c & 24) >> 1) | (c & 3);
      *(unsigned long long*)(&Kb[rowp * 40 + c4]) = pk;
      Vt[(c4 + 0) * 264 + n] = f2bf(vvv.x);
      Vt[(c4 + 1) * 264 + n] = f2bf(vvv.y);
      Vt[(c4 + 2) * 264 + n] = f2bf(vvv.z);
      Vt[(c4 + 3) * 264 + n] = f2bf(vvv.w);
    }
  }

  // ---- load Q fragments (B-operand: B[col=l16][k=quad*8+j]), scaled by 1/sqrt(d)*log2e ----
  bf16x8 qf[2];
#pragma unroll
  for (int rt = 0; rt < 2; ++rt) {
    int n = (wv << 5) + (rt << 4) + l16;
    int i = n >> 5, j = n & 31;
    int l = ((wh << 3) + i) * 256 + (ww << 5) + j;
    const float* qp = qkv + ((size_t)(b * 32768 + l)) * 192 + h * 32 + (quad << 3);
    float4 a0 = *(const float4*)qp;
    float4 a1 = *(const float4*)(qp + 4);
    bf16x8 f;
    f[0] = (short)f2bf(a0.x * QSCALE); f[1] = (short)f2bf(a0.y * QSCALE);
    f[2] = (short)f2bf(a0.z * QSCALE); f[3] = (short)f2bf(a0.w * QSCALE);
    f[4] = (short)f2bf(a1.x * QSCALE); f[5] = (short)f2bf(a1.y * QSCALE);
    f[6] = (short)f2bf(a1.z * QSCALE); f[7] = (short)f2bf(a1.w * QSCALE);
    qf[rt] = f;
  }

  __syncthreads();

  f32x4 Oacc[2][2];
#pragma unroll
  for (int rt = 0; rt < 2; ++rt) {
    Oacc[rt][0] = (f32x4){0.f, 0.f, 0.f, 0.f};
    Oacc[rt][1] = (f32x4){0.f, 0.f, 0.f, 0.f};
  }
  float lsum[2] = {0.f, 0.f};

  const unsigned short* rp = rpb + ((size_t)h << 16);
  const unsigned short* mp = maskb + ((size_t)wimg << 16);
  const float* mfp0 = maskf + ((size_t)wimg << 16);
  // bias offset within a chunk slab (ushorts) for rt=0; rt adds 512 (=16 rows*32)
  const int boff = (((wv << 5) + l16) << 5) + (quad << 3);
  const f32x4 zero = (f32x4){0.f, 0.f, 0.f, 0.f};

  for (int cc = 0; cc < 8; ++cc) {
    const int cb = cc << 5;
    const int tof = cc << 13;  // cc*8192 ushorts per chunk slab
    // bias vector loads (issued early; independent of MFMAs)
    uint4 pr[2], mr[2];
#pragma unroll
    for (int rt = 0; rt < 2; ++rt) {
      int o0 = tof + boff + (rt << 9);
      pr[rt] = *(const uint4*)(rp + o0);
      if (USEBF) mr[rt] = *(const uint4*)(mp + o0);
    }
    // K A-operand frags (row m -> token cb + 8*(m>>2)+(m&3) [kf0], +4 [kf1])
    bf16x8 kf0 = *(const bf16x8*)(&Kb[(cb + l16) * 40 + (quad << 3)]);
    bf16x8 kf1 = *(const bf16x8*)(&Kb[(cb + 16 + l16) * 40 + (quad << 3)]);
    // V B-operand frags: tokens cb + quad*8 + j, ch = l16 (vf0) / 16+l16 (vf1)
    bf16x8 vf0 = *(const bf16x8*)(&Vt[l16 * 264 + cb + (quad << 3)]);
    bf16x8 vf1 = *(const bf16x8*)(&Vt[(16 + l16) * 264 + cb + (quad << 3)]);
#pragma unroll
    for (int rt = 0; rt < 2; ++rt) {
      __builtin_amdgcn_s_setprio(1);
      f32x4 S0 = __builtin_amdgcn_mfma_f32_16x16x32_bf16(kf0, qf[rt], zero, 0, 0, 0);
      f32x4 S1 = __builtin_amdgcn_mfma_f32_16x16x32_bf16(kf1, qf[rt], zero, 0, 0, 0);
      __builtin_amdgcn_s_setprio(0);
      // S0[r] = key cb+8*quad+r,  S1[r] = key cb+8*quad+4+r,  col q = qbase+l16
      float m_[8], p_[8];
      if (USEBF) {
        m_[0] = bflo(mr[rt].x); m_[1] = bfhi(mr[rt].x);
        m_[2] = bflo(mr[rt].y); m_[3] = bfhi(mr[rt].y);
        m_[4] = bflo(mr[rt].z); m_[5] = bfhi(mr[rt].z);
        m_[6] = bflo(mr[rt].w); m_[7] = bfhi(mr[rt].w);
      } else {
        int qrow = (wv << 5) + (rt << 4) + l16;
        float4 f0 = *(const float4*)(mfp0 + (qrow << 8) + cb + (quad << 3));
        float4 f1 = *(const float4*)(mfp0 + (qrow << 8) + cb + (quad << 3) + 4);
        m_[0] = f0.x * LOG2E; m_[1] = f0.y * LOG2E; m_[2] = f0.z * LOG2E; m_[3] = f0.w * LOG2E;
        m_[4] = f1.x * LOG2E; m_[5] = f1.y * LOG2E; m_[6] = f1.z * LOG2E; m_[7] = f1.w * LOG2E;
      }
      p_[0] = bflo(pr[rt].x); p_[1] = bfhi(pr[rt].x);
      p_[2] = bflo(pr[rt].y); p_[3] = bfhi(pr[rt].y);
      p_[4] = bflo(pr[rt].z); p_[5] = bfhi(pr[rt].z);
      p_[6] = bflo(pr[rt].w); p_[7] = bfhi(pr[rt].w);
      float e[8];
#pragma unroll
      for (int r = 0; r < 4; ++r) {
        e[r]     = EXP2F(S0[r] + m_[r] + p_[r]);
        e[4 + r] = EXP2F(S1[r] + m_[4 + r] + p_[4 + r]);
      }
      lsum[rt] += ((e[0] + e[1]) + (e[2] + e[3])) + ((e[4] + e[5]) + (e[6] + e[7]));
      // lane-local PV A-frag: w[j] = bf16 pair (key cb+8*quad+2j, +2j+1), low half first
      union PF { unsigned w[4]; bf16x8 v; } u;
      u.w[0] = (unsigned)f2bf(e[0]) | ((unsigned)f2bf(e[1]) << 16);
      u.w[1] = (unsigned)f2bf(e[2]) | ((unsigned)f2bf(e[3]) << 16);
      u.w[2] = (unsigned)f2bf(e[4]) | ((unsigned)f2bf(e[5]) << 16);
      u.w[3] = (unsigned)f2bf(e[6]) | ((unsigned)f2bf(e[7]) << 16);
      __builtin_amdgcn_s_setprio(1);
      Oacc[rt][0] = __builtin_amdgcn_mfma_f32_16x16x32_bf16(u.v, vf0, Oacc[rt][0], 0, 0, 0);
      Oacc[rt][1] = __builtin_amdgcn_mfma_f32_16x16x32_bf16(u.v, vf1, Oacc[rt][1], 0, 0, 0);
      __builtin_amdgcn_s_setprio(0);
    }
  }

  // ---- finalize: lsum is per q=l16 (partial over quad); O rows at q=quad*4+r ----
#pragma unroll
  for (int rt = 0; rt < 2; ++rt) {
    float v = lsum[rt];
    v += __shfl_xor(v, 16);
    v += __shfl_xor(v, 32);
    float inv = 1.0f / v;
    int n0 = (wv << 5) + (rt << 4) + (quad << 2);
#pragma unroll
    for (int r = 0; r < 4; ++r) {
      float ir = __shfl(inv, (quad << 4) + (quad << 2) + r);
      int n = n0 + r;
      int i = n >> 5, j = n & 31;
      size_t o = ((size_t)((b * 128 + (wh << 3) + i) * 256 + (ww << 5) + j)) * 192 + h * 32 + l16;
      out[o] = Oacc[rt][0][r] * ir;
      out[o + 16] = Oacc[rt][1][r] * ir;
    }
  }
}

extern "C" void kernel_launch(void* const* d_in, const int* in_sizes, int n_in,
                              void* d_out, int out_size, void* d_ws, size_t ws_size,
                              hipStream_t stream) {
  const float* qkv = (const float*)d_in[0];
  const float* mask = (const float*)d_in[1];
  const float* rpe = (const float*)d_in[2];
  const float* pw0 = (const float*)d_in[3];
  const float* pb0 = (const float*)d_in[4];
  const float* g1 = (const float*)d_in[5];
  const float* be1 = (const float*)d_in[6];
  const float* w1 = (const float*)d_in[7];
  const float* b1 = (const float*)d_in[8];
  const float* g2 = (const float*)d_in[9];
  const float* be2 = (const float*)d_in[10];
  const float* w2 = (const float*)d_in[11];
  const float* b2 = (const float*)d_in[12];
  const float* g3 = (const float*)d_in[13];
  const float* be3 = (const float*)d_in[14];
  const float* w3 = (const float*)d_in[15];
  const float* b3 = (const float*)d_in[16];
  const int* rpi = (const int*)d_in[17];
  float* out = (float*)d_out;

  char* ws = (char*)d_ws;
  float* posT = (float*)ws;                                    // 22680 B
  unsigned short* rpb = (unsigned short*)(ws + 22784);         // 786432 B
  unsigned short* mb = (unsigned short*)(ws + 22784 + 786432); // 16777216 B
  const size_t need_mb = 22784 + 786432 + 16777216;
  const int use_bf = (ws_size >= need_mb) ? 1 : 0;

  pos_mlp_kernel<<<4, 256, 0, stream>>>(rpe, pw0, pb0, g1, be1, w1, b1, g2, be2, w2, b2,
                                        g3, be3, w3, b3, posT);
  rpb_gather_swz<<<256, 256, 0, stream>>>(rpi, posT, rpb);
  if (use_bf)
    mask_cvt_swz<<<4096, 256, 0, stream>>>(mask, (uint4*)mb);

  dim3 grid(512, 6);
  if (use_bf)
    attn_kernel<1><<<grid, 512, 0, stream>>>(qkv, mask, mb, rpb, out);
  else
    attn_kernel<0><<<grid, 512, 0, stream>>>(qkv, mask, mb, rpb, out);
}